// Round 1
// baseline (3758.937 us; speedup 1.0000x reference)
//
#include <hip/hip_runtime.h>

#define N_NODES 50000
#define N_EDGES 800000
#define IN_C 128
#define HID_C 256
#define OUT_C 128

// ---------------------------------------------------------------------------
// Edge conversion: normalize edge_index (int32 or int64, auto-detected) into
// packed int32 src[] / dst[] arrays in workspace.
// Detection: if the buffer is int64 (little-endian), the high 32-bit word of
// every value is 0 (all indices are < 2^31). Check the first 64 values.
// ---------------------------------------------------------------------------
__global__ __launch_bounds__(256) void convert_edges_k(const int* __restrict__ ei,
                                                       int* __restrict__ src,
                                                       int* __restrict__ dst) {
  __shared__ int s_is64;
  if (threadIdx.x == 0) {
    int nz = 0;
#pragma unroll
    for (int k = 0; k < 64; ++k) nz |= ei[2 * k + 1];
    s_is64 = (nz == 0) ? 1 : 0;
  }
  __syncthreads();
  const int is64 = s_is64;
  const int e = blockIdx.x * 256 + threadIdx.x;
  if (e < N_EDGES) {
    if (is64) {
      src[e] = ei[2 * e];                    // low word of edge_index[0][e]
      dst[e] = ei[2 * (N_EDGES + e)];        // low word of edge_index[1][e]
    } else {
      src[e] = ei[e];
      dst[e] = ei[N_EDGES + e];
    }
  }
}

// ---------------------------------------------------------------------------
// Degree / normalization: deg[v] = in-degree(v); dinv[v] = rsqrt(deg+1)
// (+1 = self-loop). Stored in one float buffer, transformed in place.
// ---------------------------------------------------------------------------
__global__ __launch_bounds__(256) void deg_zero_k(float* __restrict__ deg) {
  const int i = blockIdx.x * 256 + threadIdx.x;
  if (i < N_NODES) deg[i] = 0.0f;
}

__global__ __launch_bounds__(256) void deg_count_k(const int* __restrict__ dst,
                                                   float* __restrict__ deg) {
  const int e = blockIdx.x * 256 + threadIdx.x;
  if (e < N_EDGES) atomicAdd(&deg[dst[e]], 1.0f);
}

__global__ __launch_bounds__(256) void deg_rsqrt_k(float* __restrict__ deg) {
  const int i = blockIdx.x * 256 + threadIdx.x;
  if (i < N_NODES) deg[i] = rsqrtf(deg[i] + 1.0f);
}

// ---------------------------------------------------------------------------
// GEMM: H[n][m] = sum_k X[n][k] * W[m][k]   (X:[N,K] row-major, W:[M,K] row-major)
// Whole W^T staged in LDS (padded), NB=16-node x-tile staged transposed.
// Each thread: TN x 4 register tile. Optional fused ReLU on the X load.
// ---------------------------------------------------------------------------
template <int K, int M, int NB, int TN, bool RELU>
__global__ __launch_bounds__(256) void gemm_xwt_k(const float* __restrict__ X,
                                                  const float* __restrict__ W,
                                                  float* __restrict__ H) {
  constexpr int MP = M + 4;    // pad to break power-of-2 bank stride
  constexpr int NBP = NB + 4;
  __shared__ float wT[K][MP];
  __shared__ float xsT[K][NBP];
  const int tid = threadIdx.x;

  // Stage W -> wT[k][m]
  constexpr int WP4 = (M * K) / (256 * 4);
#pragma unroll
  for (int i = 0; i < WP4; ++i) {
    const int idx = (tid + i * 256) * 4;
    const int m = idx / K, k = idx % K;
    const float4 v = *(const float4*)(W + idx);
    wT[k + 0][m] = v.x;
    wT[k + 1][m] = v.y;
    wT[k + 2][m] = v.z;
    wT[k + 3][m] = v.w;
  }

  // Stage X tile -> xsT[k][n] (transposed), fused ReLU for layer 2
  const long n0 = (long)blockIdx.x * NB;
  constexpr int XP4 = (NB * K) / (256 * 4);
#pragma unroll
  for (int i = 0; i < XP4; ++i) {
    const int idx = (tid + i * 256) * 4;
    const int n = idx / K, k = idx % K;
    float4 v = *(const float4*)(X + (n0 + n) * K + k);
    if (RELU) {
      v.x = fmaxf(v.x, 0.0f);
      v.y = fmaxf(v.y, 0.0f);
      v.z = fmaxf(v.z, 0.0f);
      v.w = fmaxf(v.w, 0.0f);
    }
    xsT[k + 0][n] = v.x;
    xsT[k + 1][n] = v.y;
    xsT[k + 2][n] = v.z;
    xsT[k + 3][n] = v.w;
  }
  __syncthreads();

  constexpr int TGM = M / 4;               // thread groups along m
  const int tm = (tid % TGM) * 4;
  const int tn = (tid / TGM) * TN;

  float acc[TN][4];
#pragma unroll
  for (int n = 0; n < TN; ++n)
#pragma unroll
    for (int m = 0; m < 4; ++m) acc[n][m] = 0.0f;

#pragma unroll 4
  for (int k = 0; k < K; ++k) {
    const float4 wv = *(const float4*)&wT[k][tm];
    float xv[TN];
    if constexpr (TN == 4) {
      const float4 t = *(const float4*)&xsT[k][tn];
      xv[0] = t.x; xv[1] = t.y; xv[2] = t.z; xv[3] = t.w;
    } else {
      const float2 t = *(const float2*)&xsT[k][tn];
      xv[0] = t.x; xv[1] = t.y;
    }
#pragma unroll
    for (int n = 0; n < TN; ++n) {
      acc[n][0] += xv[n] * wv.x;
      acc[n][1] += xv[n] * wv.y;
      acc[n][2] += xv[n] * wv.z;
      acc[n][3] += xv[n] * wv.w;
    }
  }

#pragma unroll
  for (int n = 0; n < TN; ++n) {
    const float4 o = {acc[n][0], acc[n][1], acc[n][2], acc[n][3]};
    *(float4*)(H + (n0 + tn + n) * M + tm) = o;
  }
}

// ---------------------------------------------------------------------------
// Aggregation init: out[v][c] = bias[c] + dinv[v]^2 * h[v][c]  (self-loop term)
// ---------------------------------------------------------------------------
template <int C>
__global__ __launch_bounds__(256) void self_init_k(const float* __restrict__ h,
                                                   const float* __restrict__ dinv,
                                                   const float* __restrict__ bias,
                                                   float* __restrict__ out) {
  const long t = (long)blockIdx.x * 256 + threadIdx.x;
  const long idx = t * 4;
  if (idx >= (long)N_NODES * C) return;
  const int v = (int)(idx / C);
  const int c = (int)(idx % C);
  const float di = dinv[v];
  const float s = di * di;
  const float4 hv = *(const float4*)(h + idx);
  const float4 bv = *(const float4*)(bias + c);
  const float4 o = {bv.x + s * hv.x, bv.y + s * hv.y, bv.z + s * hv.z,
                    bv.w + s * hv.w};
  *(float4*)(out + idx) = o;
}

// ---------------------------------------------------------------------------
// Edge scatter: out[dst] += dinv[src]*dinv[dst] * h[src]; one wave per edge,
// each lane handles C/64 channels.
// ---------------------------------------------------------------------------
template <int C>
__global__ __launch_bounds__(256) void scatter_edges_k(const int* __restrict__ src,
                                                       const int* __restrict__ dst,
                                                       const float* __restrict__ dinv,
                                                       const float* __restrict__ h,
                                                       float* __restrict__ out) {
  const int e = blockIdx.x * 4 + (threadIdx.x >> 6);
  if (e >= N_EDGES) return;
  const int lane = threadIdx.x & 63;
  const int s = src[e];
  const int d = dst[e];
  const float nrm = dinv[s] * dinv[d];
  constexpr int LPE = C / 64;  // floats per lane
  const float* hp = h + (long)s * C + lane * LPE;
  float* op = out + (long)d * C + lane * LPE;
  if constexpr (LPE == 4) {
    const float4 v = *(const float4*)hp;
    atomicAdd(op + 0, v.x * nrm);
    atomicAdd(op + 1, v.y * nrm);
    atomicAdd(op + 2, v.z * nrm);
    atomicAdd(op + 3, v.w * nrm);
  } else {
    const float2 v = *(const float2*)hp;
    atomicAdd(op + 0, v.x * nrm);
    atomicAdd(op + 1, v.y * nrm);
  }
}

// ---------------------------------------------------------------------------
extern "C" void kernel_launch(void* const* d_in, const int* in_sizes, int n_in,
                              void* d_out, int out_size, void* d_ws, size_t ws_size,
                              hipStream_t stream) {
  (void)in_sizes; (void)n_in; (void)out_size; (void)ws_size;

  const float* x  = (const float*)d_in[0];
  const int*   ei = (const int*)d_in[1];
  const float* W1 = (const float*)d_in[2];
  const float* b1 = (const float*)d_in[3];
  const float* W2 = (const float*)d_in[4];
  const float* b2 = (const float*)d_in[5];
  float* out = (float*)d_out;

  // Workspace layout (bytes, all 16B-aligned):
  char* ws = (char*)d_ws;
  int*   src  = (int*)(ws + 0);                    //  3.2 MB
  int*   dst  = (int*)(ws + 3200000);              //  3.2 MB
  float* dinv = (float*)(ws + 6400000);            //  0.2 MB (deg -> dinv)
  float* h    = (float*)(ws + 6600000);            // 51.2 MB (h1, reused as h2)
  float* agg1 = (float*)(ws + 57800000);           // 51.2 MB

  const int EB = (N_EDGES + 255) / 256;   // 3125
  const int NBK = (N_NODES + 255) / 256;  // 196

  convert_edges_k<<<EB, 256, 0, stream>>>(ei, src, dst);
  deg_zero_k<<<NBK, 256, 0, stream>>>(dinv);
  deg_count_k<<<EB, 256, 0, stream>>>(dst, dinv);
  deg_rsqrt_k<<<NBK, 256, 0, stream>>>(dinv);

  // ---- Layer 1: h1 = x @ W1^T ; agg1 = b1 + dinv^2*h1 + scatter ----
  gemm_xwt_k<IN_C, HID_C, 16, 4, false><<<N_NODES / 16, 256, 0, stream>>>(x, W1, h);
  self_init_k<HID_C><<<(N_NODES * HID_C / 4 + 255) / 256, 256, 0, stream>>>(h, dinv, b1, agg1);
  scatter_edges_k<HID_C><<<N_EDGES / 4, 256, 0, stream>>>(src, dst, dinv, h, agg1);

  // ---- Layer 2: h2 = relu(agg1) @ W2^T ; out = b2 + dinv^2*h2 + scatter ----
  gemm_xwt_k<HID_C, OUT_C, 16, 2, true><<<N_NODES / 16, 256, 0, stream>>>(agg1, W2, h);
  self_init_k<OUT_C><<<(N_NODES * OUT_C / 4 + 255) / 256, 256, 0, stream>>>(h, dinv, b2, out);
  scatter_edges_k<OUT_C><<<N_EDGES / 4, 256, 0, stream>>>(src, dst, dinv, h, out);
}

// Round 4
// 783.744 us; speedup vs baseline: 4.7961x; 4.7961x over previous
//
#include <hip/hip_runtime.h>

#define N_NODES 50000
#define N_EDGES 800000
#define IN_C 128
#define HID_C 256
#define OUT_C 128

// ---------------------------------------------------------------------------
// Edge conversion: normalize edge_index (int32 or int64, auto-detected) into
// packed int32 src[] / dst[] arrays in workspace.
// Detection: if the buffer is int64 (little-endian), the high 32-bit word of
// every value is 0 (all indices < 2^31). Check the first 64 values.
// ---------------------------------------------------------------------------
__global__ __launch_bounds__(256) void convert_edges_k(const int* __restrict__ ei,
                                                       int* __restrict__ src,
                                                       int* __restrict__ dst) {
  __shared__ int s_is64;
  if (threadIdx.x == 0) {
    int nz = 0;
#pragma unroll
    for (int k = 0; k < 64; ++k) nz |= ei[2 * k + 1];
    s_is64 = (nz == 0) ? 1 : 0;
  }
  __syncthreads();
  const int is64 = s_is64;
  const int e = blockIdx.x * 256 + threadIdx.x;
  if (e < N_EDGES) {
    if (is64) {
      src[e] = ei[2 * e];                    // low word of edge_index[0][e]
      dst[e] = ei[2 * (N_EDGES + e)];        // low word of edge_index[1][e]
    } else {
      src[e] = ei[e];
      dst[e] = ei[N_EDGES + e];
    }
  }
}

// ---------------------------------------------------------------------------
// Degree histogram (int), then dinv[v] = rsqrt(deg[v] + 1)   (+1 = self-loop)
// ---------------------------------------------------------------------------
__global__ __launch_bounds__(256) void deg_zero_k(int* __restrict__ deg) {
  const int i = blockIdx.x * 256 + threadIdx.x;
  if (i < N_NODES) deg[i] = 0;
}

__global__ __launch_bounds__(256) void deg_count_k(const int* __restrict__ dst,
                                                   int* __restrict__ deg) {
  const int e = blockIdx.x * 256 + threadIdx.x;
  if (e < N_EDGES) atomicAdd(&deg[dst[e]], 1);
}

__global__ __launch_bounds__(256) void dinv_k(const int* __restrict__ deg,
                                              float* __restrict__ dinv) {
  const int i = blockIdx.x * 256 + threadIdx.x;
  if (i < N_NODES) dinv[i] = rsqrtf((float)deg[i] + 1.0f);
}

// ---------------------------------------------------------------------------
// Exclusive prefix scan over deg[0..N) -> rowstart[0..N], cursor = rowstart.
// Single block of 1024 threads; each thread owns a contiguous chunk.
// ---------------------------------------------------------------------------
__global__ __launch_bounds__(1024) void scan_k(const int* __restrict__ deg,
                                               int* __restrict__ rowstart,
                                               int* __restrict__ cursor) {
  __shared__ int part[1024];
  const int t = threadIdx.x;
  constexpr int IT = (N_NODES + 1023) / 1024;  // 49
  const int base = t * IT;

  int s = 0;
  for (int i = 0; i < IT; ++i) {
    const int idx = base + i;
    if (idx < N_NODES) s += deg[idx];
  }
  part[t] = s;
  __syncthreads();
  // Hillis-Steele inclusive scan over 1024 partials
  for (int off = 1; off < 1024; off <<= 1) {
    const int tmp = (t >= off) ? part[t - off] : 0;
    __syncthreads();
    part[t] += tmp;
    __syncthreads();
  }
  int run = part[t] - s;  // exclusive base for this thread's chunk
  for (int i = 0; i < IT; ++i) {
    const int idx = base + i;
    if (idx < N_NODES) {
      rowstart[idx] = run;
      cursor[idx] = run;
      run += deg[idx];
    }
  }
  if (t == 1023) rowstart[N_NODES] = part[1023];
}

// ---------------------------------------------------------------------------
// CSR fill: bucket edges by destination. Order within a bucket is arbitrary
// (atomic arrival) — fp32 sum-order variation is well inside the tolerance.
// ---------------------------------------------------------------------------
__global__ __launch_bounds__(256) void fill_csr_k(const int* __restrict__ src,
                                                  const int* __restrict__ dst,
                                                  int* __restrict__ cursor,
                                                  int* __restrict__ csr_src) {
  const int e = blockIdx.x * 256 + threadIdx.x;
  if (e < N_EDGES) {
    const int pos = atomicAdd(&cursor[dst[e]], 1);
    csr_src[pos] = src[e];
  }
}

// ---------------------------------------------------------------------------
// GEMM: H[n][m] = sum_k X[n][k] * W[m][k]   (X:[N,K] row-major, W:[M,K] row-major)
// Whole W^T staged in LDS (padded), NB=16-node x-tile staged transposed.
// Each thread: TN x 4 register tile. Optional fused ReLU on the X load.
// ---------------------------------------------------------------------------
template <int K, int M, int NB, int TN, bool RELU>
__global__ __launch_bounds__(256) void gemm_xwt_k(const float* __restrict__ X,
                                                  const float* __restrict__ W,
                                                  float* __restrict__ H) {
  constexpr int MP = M + 4;
  constexpr int NBP = NB + 4;
  __shared__ float wT[K][MP];
  __shared__ float xsT[K][NBP];
  const int tid = threadIdx.x;

  constexpr int WP4 = (M * K) / (256 * 4);
#pragma unroll
  for (int i = 0; i < WP4; ++i) {
    const int idx = (tid + i * 256) * 4;
    const int m = idx / K, k = idx % K;
    const float4 v = *(const float4*)(W + idx);
    wT[k + 0][m] = v.x;
    wT[k + 1][m] = v.y;
    wT[k + 2][m] = v.z;
    wT[k + 3][m] = v.w;
  }

  const long n0 = (long)blockIdx.x * NB;
  constexpr int XP4 = (NB * K) / (256 * 4);
#pragma unroll
  for (int i = 0; i < XP4; ++i) {
    const int idx = (tid + i * 256) * 4;
    const int n = idx / K, k = idx % K;
    float4 v = *(const float4*)(X + (n0 + n) * K + k);
    if (RELU) {
      v.x = fmaxf(v.x, 0.0f);
      v.y = fmaxf(v.y, 0.0f);
      v.z = fmaxf(v.z, 0.0f);
      v.w = fmaxf(v.w, 0.0f);
    }
    xsT[k + 0][n] = v.x;
    xsT[k + 1][n] = v.y;
    xsT[k + 2][n] = v.z;
    xsT[k + 3][n] = v.w;
  }
  __syncthreads();

  constexpr int TGM = M / 4;
  const int tm = (tid % TGM) * 4;
  const int tn = (tid / TGM) * TN;

  float acc[TN][4];
#pragma unroll
  for (int n = 0; n < TN; ++n)
#pragma unroll
    for (int m = 0; m < 4; ++m) acc[n][m] = 0.0f;

#pragma unroll 4
  for (int k = 0; k < K; ++k) {
    const float4 wv = *(const float4*)&wT[k][tm];
    float xv[TN];
    if constexpr (TN == 4) {
      const float4 t = *(const float4*)&xsT[k][tn];
      xv[0] = t.x; xv[1] = t.y; xv[2] = t.z; xv[3] = t.w;
    } else {
      const float2 t = *(const float2*)&xsT[k][tn];
      xv[0] = t.x; xv[1] = t.y;
    }
#pragma unroll
    for (int n = 0; n < TN; ++n) {
      acc[n][0] += xv[n] * wv.x;
      acc[n][1] += xv[n] * wv.y;
      acc[n][2] += xv[n] * wv.z;
      acc[n][3] += xv[n] * wv.w;
    }
  }

#pragma unroll
  for (int n = 0; n < TN; ++n) {
    const float4 o = {acc[n][0], acc[n][1], acc[n][2], acc[n][3]};
    *(float4*)(H + (n0 + tn + n) * M + tm) = o;
  }
}

// ---------------------------------------------------------------------------
// Gather-aggregate: one wave per destination node.
// out[v][:] = bias + dinv[v]^2 * h[v][:] + sum_{e: dst=v} dinv[v]*dinv[src] * h[src][:]
// No atomics; each output row written exactly once.
// ---------------------------------------------------------------------------
template <int C>
__global__ __launch_bounds__(256) void gather_k(const int* __restrict__ rowstart,
                                                const int* __restrict__ csr_src,
                                                const float* __restrict__ dinv,
                                                const float* __restrict__ h,
                                                const float* __restrict__ bias,
                                                float* __restrict__ out) {
  const int v = (blockIdx.x * 256 + threadIdx.x) >> 6;  // one wave per node
  if (v >= N_NODES) return;
  const int lane = threadIdx.x & 63;
  constexpr int LPE = C / 64;  // floats per lane (4 or 2)
  const int rs = rowstart[v];
  const int re = rowstart[v + 1];
  const float dv = dinv[v];

  float acc[LPE];
#pragma unroll
  for (int i = 0; i < LPE; ++i) acc[i] = 0.0f;

  int e = rs;
  for (; e + 1 < re; e += 2) {  // 2-edge unroll: two independent row loads in flight
    const int s0 = csr_src[e];
    const int s1 = csr_src[e + 1];
    const float n0 = dv * dinv[s0];
    const float n1 = dv * dinv[s1];
    const float* p0 = h + (long)s0 * C + lane * LPE;
    const float* p1 = h + (long)s1 * C + lane * LPE;
    if constexpr (LPE == 4) {
      const float4 a = *(const float4*)p0;
      const float4 b = *(const float4*)p1;
      acc[0] += n0 * a.x + n1 * b.x;
      acc[1] += n0 * a.y + n1 * b.y;
      acc[2] += n0 * a.z + n1 * b.z;
      acc[3] += n0 * a.w + n1 * b.w;
    } else {
      const float2 a = *(const float2*)p0;
      const float2 b = *(const float2*)p1;
      acc[0] += n0 * a.x + n1 * b.x;
      acc[1] += n0 * a.y + n1 * b.y;
    }
  }
  if (e < re) {
    const int s0 = csr_src[e];
    const float n0 = dv * dinv[s0];
    const float* p0 = h + (long)s0 * C + lane * LPE;
    if constexpr (LPE == 4) {
      const float4 a = *(const float4*)p0;
      acc[0] += n0 * a.x;
      acc[1] += n0 * a.y;
      acc[2] += n0 * a.z;
      acc[3] += n0 * a.w;
    } else {
      const float2 a = *(const float2*)p0;
      acc[0] += n0 * a.x;
      acc[1] += n0 * a.y;
    }
  }

  // Epilogue: bias + self-loop term, single write of the output row.
  const float s2 = dv * dv;
  const float* hp = h + (long)v * C + lane * LPE;
  const float* bp = bias + lane * LPE;
  float* op = out + (long)v * C + lane * LPE;
  if constexpr (LPE == 4) {
    const float4 hv = *(const float4*)hp;
    const float4 bv = *(const float4*)bp;
    const float4 o = {bv.x + s2 * hv.x + acc[0], bv.y + s2 * hv.y + acc[1],
                      bv.z + s2 * hv.z + acc[2], bv.w + s2 * hv.w + acc[3]};
    *(float4*)op = o;
  } else {
    const float2 hv = *(const float2*)hp;
    const float2 bv = *(const float2*)bp;
    const float2 o = {bv.x + s2 * hv.x + acc[0], bv.y + s2 * hv.y + acc[1]};
    *(float2*)op = o;
  }
}

// ---------------------------------------------------------------------------
extern "C" void kernel_launch(void* const* d_in, const int* in_sizes, int n_in,
                              void* d_out, int out_size, void* d_ws, size_t ws_size,
                              hipStream_t stream) {
  (void)in_sizes; (void)n_in; (void)out_size; (void)ws_size;

  const float* x  = (const float*)d_in[0];
  const int*   ei = (const int*)d_in[1];
  const float* W1 = (const float*)d_in[2];
  const float* b1 = (const float*)d_in[3];
  const float* W2 = (const float*)d_in[4];
  const float* b2 = (const float*)d_in[5];
  float* out = (float*)d_out;

  // Workspace layout (bytes, 16B-aligned):
  char* ws = (char*)d_ws;
  int*   src      = (int*)(ws + 0);            //  3.2 MB
  int*   dst      = (int*)(ws + 3200000);      //  3.2 MB
  int*   csr_src  = (int*)(ws + 6400000);      //  3.2 MB
  int*   deg      = (int*)(ws + 9600000);      //  0.2 MB
  int*   rowstart = (int*)(ws + 9800000);      //  0.2 MB (N+1 ints)
  int*   cursor   = (int*)(ws + 10000016);     //  0.2 MB
  float* dinv     = (float*)(ws + 10200016);   //  0.2 MB
  float* h        = (float*)(ws + 10400016);   // 51.2 MB (h1, reused as h2)
  float* agg1     = (float*)(ws + 61600016);   // 51.2 MB

  const int EB = (N_EDGES + 255) / 256;   // 3125
  const int NBK = (N_NODES + 255) / 256;  // 196

  // ---- Graph preprocessing: CSR by destination ----
  convert_edges_k<<<EB, 256, 0, stream>>>(ei, src, dst);
  deg_zero_k<<<NBK, 256, 0, stream>>>(deg);
  deg_count_k<<<EB, 256, 0, stream>>>(dst, deg);
  dinv_k<<<NBK, 256, 0, stream>>>(deg, dinv);
  scan_k<<<1, 1024, 0, stream>>>(deg, rowstart, cursor);
  fill_csr_k<<<EB, 256, 0, stream>>>(src, dst, cursor, csr_src);

  const int GB = (N_NODES + 3) / 4;  // 4 waves/block, 1 node/wave

  // ---- Layer 1: h1 = x @ W1^T ; agg1 = b1 + norm-aggregate(h1) ----
  gemm_xwt_k<IN_C, HID_C, 16, 4, false><<<N_NODES / 16, 256, 0, stream>>>(x, W1, h);
  gather_k<HID_C><<<GB, 256, 0, stream>>>(rowstart, csr_src, dinv, h, b1, agg1);

  // ---- Layer 2: h2 = relu(agg1) @ W2^T ; out = b2 + norm-aggregate(h2) ----
  gemm_xwt_k<HID_C, OUT_C, 16, 2, true><<<N_NODES / 16, 256, 0, stream>>>(agg1, W2, h);
  gather_k<OUT_C><<<GB, 256, 0, stream>>>(rowstart, csr_src, dinv, h, b2, out);
}

// Round 9
// 506.531 us; speedup vs baseline: 7.4209x; 1.5473x over previous
//
#include <hip/hip_runtime.h>

#define N_NODES 50000
#define N_EDGES 800000
#define IN_C 128
#define HID_C 256
#define OUT_C 128

// ---------------------------------------------------------------------------
// Edge conversion (int32/int64 auto-detect) fused with dst-degree histogram.
// deg must be zeroed beforehand.
// ---------------------------------------------------------------------------
__global__ __launch_bounds__(256) void deg_zero_k(int* __restrict__ deg) {
  const int i = blockIdx.x * 256 + threadIdx.x;
  if (i < N_NODES) deg[i] = 0;
}

__global__ __launch_bounds__(256) void convert_count_k(const int* __restrict__ ei,
                                                       int* __restrict__ src,
                                                       int* __restrict__ dst,
                                                       int* __restrict__ deg) {
  __shared__ int s_is64;
  if (threadIdx.x == 0) {
    int nz = 0;
#pragma unroll
    for (int k = 0; k < 64; ++k) nz |= ei[2 * k + 1];
    s_is64 = (nz == 0) ? 1 : 0;
  }
  __syncthreads();
  const int is64 = s_is64;
  const int e = blockIdx.x * 256 + threadIdx.x;
  if (e < N_EDGES) {
    int s, d;
    if (is64) {
      s = ei[2 * e];                  // low word of edge_index[0][e]
      d = ei[2 * (N_EDGES + e)];      // low word of edge_index[1][e]
    } else {
      s = ei[e];
      d = ei[N_EDGES + e];
    }
    src[e] = s;
    dst[e] = d;
    atomicAdd(&deg[d], 1);
  }
}

// ---------------------------------------------------------------------------
// Exclusive scan over deg -> rowstart/cursor, fused dinv = rsqrt(deg+1).
// Single block of 1024 threads.
// ---------------------------------------------------------------------------
__global__ __launch_bounds__(1024) void scan_dinv_k(const int* __restrict__ deg,
                                                    int* __restrict__ rowstart,
                                                    int* __restrict__ cursor,
                                                    float* __restrict__ dinv) {
  __shared__ int part[1024];
  const int t = threadIdx.x;
  constexpr int IT = (N_NODES + 1023) / 1024;  // 49
  const int base = t * IT;

  int s = 0;
  for (int i = 0; i < IT; ++i) {
    const int idx = base + i;
    if (idx < N_NODES) s += deg[idx];
  }
  part[t] = s;
  __syncthreads();
  for (int off = 1; off < 1024; off <<= 1) {
    const int tmp = (t >= off) ? part[t - off] : 0;
    __syncthreads();
    part[t] += tmp;
    __syncthreads();
  }
  int run = part[t] - s;
  for (int i = 0; i < IT; ++i) {
    const int idx = base + i;
    if (idx < N_NODES) {
      const int d = deg[idx];
      rowstart[idx] = run;
      cursor[idx] = run;
      dinv[idx] = rsqrtf((float)d + 1.0f);
      run += d;
    }
  }
  if (t == 1023) rowstart[N_NODES] = part[1023];
}

__global__ __launch_bounds__(256) void fill_csr_k(const int* __restrict__ src,
                                                  const int* __restrict__ dst,
                                                  int* __restrict__ cursor,
                                                  int* __restrict__ csr_src) {
  const int e = blockIdx.x * 256 + threadIdx.x;
  if (e < N_EDGES) {
    const int pos = atomicAdd(&cursor[dst[e]], 1);
    csr_src[pos] = src[e];
  }
}

// ---------------------------------------------------------------------------
// Tiled SGEMM: H[n][m] = sum_k X[n][k]*W[m][k]  (+bias, relu optional)
// Tile: 128 nodes x 64 out-chans, BK=32. 256 threads, 8n x 4m per thread.
// LDS: As[32][132] + Bs[32][68] = 25.6 KB -> ~6 blocks/CU.
// ---------------------------------------------------------------------------
template <int K, int MTOT, bool BIASRELU>
__global__ __launch_bounds__(256) void gemm_tiled_k(const float* __restrict__ X,
                                                    const float* __restrict__ W,
                                                    const float* __restrict__ bias,
                                                    float* __restrict__ H) {
  constexpr int NT = 128, MT = 64, KT = 32;
  __shared__ float As[KT][NT + 4];
  __shared__ float Bs[KT][MT + 4];
  const int tid = threadIdx.x;
  const long n0 = (long)blockIdx.x * NT;
  const int m0 = blockIdx.y * MT;
  const int kq = tid & 7;       // k-quad within 32-k tile
  const int rowi = tid >> 3;    // 0..31
  const int tm = (tid & 15) * 4;  // m offset 0..60
  const int tn = (tid >> 4) * 4;  // n offset 0..60 (plus +64 half)

  float acc[8][4];
#pragma unroll
  for (int i = 0; i < 8; ++i)
#pragma unroll
    for (int j = 0; j < 4; ++j) acc[i][j] = 0.0f;

  for (int ks = 0; ks < K / KT; ++ks) {
    const int k0 = ks * KT;
    if (ks) __syncthreads();
    // Stage X-tile (128 rows x 32 k), transposed into As[k][n]
#pragma unroll
    for (int r = 0; r < 4; ++r) {
      const int nr = rowi + r * 32;
      long ng = n0 + nr;
      if (ng > N_NODES - 1) ng = N_NODES - 1;  // clamp; stores guarded
      const float4 v = *(const float4*)(X + ng * K + k0 + kq * 4);
      As[kq * 4 + 0][nr] = v.x;
      As[kq * 4 + 1][nr] = v.y;
      As[kq * 4 + 2][nr] = v.z;
      As[kq * 4 + 3][nr] = v.w;
    }
    // Stage W-tile (64 rows x 32 k), transposed into Bs[k][m]
#pragma unroll
    for (int r = 0; r < 2; ++r) {
      const int mr = rowi + r * 32;
      const float4 v = *(const float4*)(W + (long)(m0 + mr) * K + k0 + kq * 4);
      Bs[kq * 4 + 0][mr] = v.x;
      Bs[kq * 4 + 1][mr] = v.y;
      Bs[kq * 4 + 2][mr] = v.z;
      Bs[kq * 4 + 3][mr] = v.w;
    }
    __syncthreads();

#pragma unroll 4
    for (int k = 0; k < KT; ++k) {
      const float4 a0 = *(const float4*)&As[k][tn];
      const float4 a1 = *(const float4*)&As[k][tn + 64];
      const float4 b0 = *(const float4*)&Bs[k][tm];
      const float an[8] = {a0.x, a0.y, a0.z, a0.w, a1.x, a1.y, a1.z, a1.w};
      const float bm[4] = {b0.x, b0.y, b0.z, b0.w};
#pragma unroll
      for (int i = 0; i < 8; ++i)
#pragma unroll
        for (int j = 0; j < 4; ++j) acc[i][j] += an[i] * bm[j];
    }
  }

  float4 bv = {0.0f, 0.0f, 0.0f, 0.0f};
  if (BIASRELU) bv = *(const float4*)(bias + m0 + tm);
#pragma unroll
  for (int i = 0; i < 8; ++i) {
    const long ng = n0 + tn + (i & 3) + (i >> 2) * 64;
    if (ng < N_NODES) {
      float4 o = {acc[i][0], acc[i][1], acc[i][2], acc[i][3]};
      if (BIASRELU) {
        o.x = fmaxf(o.x + bv.x, 0.0f);
        o.y = fmaxf(o.y + bv.y, 0.0f);
        o.z = fmaxf(o.z + bv.z, 0.0f);
        o.w = fmaxf(o.w + bv.w, 0.0f);
      }
      *(float4*)(H + ng * MTOT + m0 + tm) = o;
    }
  }
}

// ---------------------------------------------------------------------------
// Gather-aggregate (one wave per destination node), C=128 -> 2 floats/lane.
// out[v] = (bias) + dinv[v]^2 * h[v] + sum_{e: dst=v} dinv[v]*dinv[src]*h[src]
// ---------------------------------------------------------------------------
template <int C, bool HAS_BIAS>
__global__ __launch_bounds__(256) void gather_k(const int* __restrict__ rowstart,
                                                const int* __restrict__ csr_src,
                                                const float* __restrict__ dinv,
                                                const float* __restrict__ h,
                                                const float* __restrict__ bias,
                                                float* __restrict__ out) {
  const int v = (blockIdx.x * 256 + threadIdx.x) >> 6;
  if (v >= N_NODES) return;
  const int lane = threadIdx.x & 63;
  constexpr int LPE = C / 64;
  const int rs = rowstart[v];
  const int re = rowstart[v + 1];
  const float dv = dinv[v];

  float acc[LPE];
#pragma unroll
  for (int i = 0; i < LPE; ++i) acc[i] = 0.0f;

  int e = rs;
  for (; e + 1 < re; e += 2) {
    const int s0 = csr_src[e];
    const int s1 = csr_src[e + 1];
    const float n0 = dv * dinv[s0];
    const float n1 = dv * dinv[s1];
    const float* p0 = h + (long)s0 * C + lane * LPE;
    const float* p1 = h + (long)s1 * C + lane * LPE;
    if constexpr (LPE == 4) {
      const float4 a = *(const float4*)p0;
      const float4 b = *(const float4*)p1;
      acc[0] += n0 * a.x + n1 * b.x;
      acc[1] += n0 * a.y + n1 * b.y;
      acc[2] += n0 * a.z + n1 * b.z;
      acc[3] += n0 * a.w + n1 * b.w;
    } else {
      const float2 a = *(const float2*)p0;
      const float2 b = *(const float2*)p1;
      acc[0] += n0 * a.x + n1 * b.x;
      acc[1] += n0 * a.y + n1 * b.y;
    }
  }
  if (e < re) {
    const int s0 = csr_src[e];
    const float n0 = dv * dinv[s0];
    const float* p0 = h + (long)s0 * C + lane * LPE;
    if constexpr (LPE == 4) {
      const float4 a = *(const float4*)p0;
      acc[0] += n0 * a.x;
      acc[1] += n0 * a.y;
      acc[2] += n0 * a.z;
      acc[3] += n0 * a.w;
    } else {
      const float2 a = *(const float2*)p0;
      acc[0] += n0 * a.x;
      acc[1] += n0 * a.y;
    }
  }

  const float s2 = dv * dv;
  const float* hp = h + (long)v * C + lane * LPE;
  float* op = out + (long)v * C + lane * LPE;
  if constexpr (LPE == 4) {
    const float4 hv = *(const float4*)hp;
    float4 o = {s2 * hv.x + acc[0], s2 * hv.y + acc[1], s2 * hv.z + acc[2],
                s2 * hv.w + acc[3]};
    if (HAS_BIAS) {
      const float4 bv = *(const float4*)(bias + lane * LPE);
      o.x += bv.x; o.y += bv.y; o.z += bv.z; o.w += bv.w;
    }
    *(float4*)op = o;
  } else {
    const float2 hv = *(const float2*)hp;
    float2 o = {s2 * hv.x + acc[0], s2 * hv.y + acc[1]};
    if (HAS_BIAS) {
      const float2 bv = *(const float2*)(bias + lane * LPE);
      o.x += bv.x; o.y += bv.y;
    }
    *(float2*)op = o;
  }
}

// ---------------------------------------------------------------------------
extern "C" void kernel_launch(void* const* d_in, const int* in_sizes, int n_in,
                              void* d_out, int out_size, void* d_ws, size_t ws_size,
                              hipStream_t stream) {
  (void)in_sizes; (void)n_in; (void)out_size; (void)ws_size;

  const float* x  = (const float*)d_in[0];
  const int*   ei = (const int*)d_in[1];
  const float* W1 = (const float*)d_in[2];
  const float* b1 = (const float*)d_in[3];
  const float* W2 = (const float*)d_in[4];
  const float* b2 = (const float*)d_in[5];
  float* out = (float*)d_out;

  // Workspace layout (bytes, 16B-aligned):
  char* ws = (char*)d_ws;
  int*   src      = (int*)(ws + 0);            //  3.2 MB
  int*   dst      = (int*)(ws + 3200000);      //  3.2 MB
  int*   csr_src  = (int*)(ws + 6400000);      //  3.2 MB
  int*   deg      = (int*)(ws + 9600000);      //  0.2 MB
  int*   rowstart = (int*)(ws + 9800000);      //  0.2 MB (N+1 ints)
  int*   cursor   = (int*)(ws + 10000016);     //  0.2 MB
  float* dinv     = (float*)(ws + 10200016);   //  0.2 MB
  float* aggx     = (float*)(ws + 10400016);   // 25.6 MB (agg_x; reused as h2)
  float* h1       = (float*)(ws + 36000016);   // 51.2 MB
  float* h2       = aggx;                      // alias: aggx dead after gemm1

  const int EB  = (N_EDGES + 255) / 256;  // 3125
  const int NBK = (N_NODES + 255) / 256;  // 196
  const int GB  = (N_NODES + 3) / 4;      // gather: 4 waves/block, 1 node/wave
  const int NTB = (N_NODES + 127) / 128;  // 391 node-tiles for GEMM

  // ---- Graph preprocessing: CSR by destination + dinv ----
  deg_zero_k<<<NBK, 256, 0, stream>>>(deg);
  convert_count_k<<<EB, 256, 0, stream>>>(ei, src, dst, deg);
  scan_dinv_k<<<1, 1024, 0, stream>>>(deg, rowstart, cursor, dinv);
  fill_csr_k<<<EB, 256, 0, stream>>>(src, dst, cursor, csr_src);

  // ---- Layer 1 (aggregate-first: agg(x)@W1^T == agg(x@W1^T)) ----
  gather_k<IN_C, false><<<GB, 256, 0, stream>>>(rowstart, csr_src, dinv, x,
                                                nullptr, aggx);
  gemm_tiled_k<IN_C, HID_C, true>
      <<<dim3(NTB, HID_C / 64), 256, 0, stream>>>(aggx, W1, b1, h1);

  // ---- Layer 2 (transform-first) ----
  gemm_tiled_k<HID_C, OUT_C, false>
      <<<dim3(NTB, OUT_C / 64), 256, 0, stream>>>(h1, W2, nullptr, h2);
  gather_k<OUT_C, true><<<GB, 256, 0, stream>>>(rowstart, csr_src, dinv, h2,
                                                b2, out);
}

// Round 10
// 379.805 us; speedup vs baseline: 9.8970x; 1.3337x over previous
//
#include <hip/hip_runtime.h>

#define N_NODES 50000
#define N_EDGES 800000
#define IN_C 128
#define HID_C 256
#define OUT_C 128
#define NBLK 196  // ceil(N_NODES / 256)

// ---------------------------------------------------------------------------
// Edge conversion (int32/int64 auto-detect) fused with dst-degree histogram.
// ---------------------------------------------------------------------------
__global__ __launch_bounds__(256) void deg_zero_k(int* __restrict__ deg) {
  const int i = blockIdx.x * 256 + threadIdx.x;
  if (i < N_NODES) deg[i] = 0;
}

__global__ __launch_bounds__(256) void convert_count_k(const int* __restrict__ ei,
                                                       int* __restrict__ src,
                                                       int* __restrict__ dst,
                                                       int* __restrict__ deg) {
  __shared__ int s_is64;
  if (threadIdx.x == 0) {
    int nz = 0;
#pragma unroll
    for (int k = 0; k < 64; ++k) nz |= ei[2 * k + 1];
    s_is64 = (nz == 0) ? 1 : 0;
  }
  __syncthreads();
  const int is64 = s_is64;
  const int e = blockIdx.x * 256 + threadIdx.x;
  if (e < N_EDGES) {
    int s, d;
    if (is64) {
      s = ei[2 * e];                  // low word of edge_index[0][e]
      d = ei[2 * (N_EDGES + e)];      // low word of edge_index[1][e]
    } else {
      s = ei[e];
      d = ei[N_EDGES + e];
    }
    src[e] = s;
    dst[e] = d;
    atomicAdd(&deg[d], 1);
  }
}

// ---------------------------------------------------------------------------
// Parallel 3-phase exclusive scan over deg[0..N) (replaces single-block scan):
//   bsum_k:  per-256-chunk sums             (196 blocks)
//   bscan_k: scan the 196 partials          (1 block)
//   bfinal_k: in-block scan + offset, fused dinv = rsqrt(deg+1)
// ---------------------------------------------------------------------------
__global__ __launch_bounds__(256) void bsum_k(const int* __restrict__ deg,
                                              int* __restrict__ bsum) {
  const int i = blockIdx.x * 256 + threadIdx.x;
  int v = (i < N_NODES) ? deg[i] : 0;
#pragma unroll
  for (int off = 32; off > 0; off >>= 1) v += __shfl_down(v, off, 64);
  __shared__ int ws[4];
  if ((threadIdx.x & 63) == 0) ws[threadIdx.x >> 6] = v;
  __syncthreads();
  if (threadIdx.x == 0) bsum[blockIdx.x] = ws[0] + ws[1] + ws[2] + ws[3];
}

__global__ __launch_bounds__(256) void bscan_k(const int* __restrict__ bsum,
                                               int* __restrict__ boff) {
  __shared__ int s[256];
  const int t = threadIdx.x;
  const int v = (t < NBLK) ? bsum[t] : 0;
  s[t] = v;
  __syncthreads();
  for (int off = 1; off < 256; off <<= 1) {
    const int tmp = (t >= off) ? s[t - off] : 0;
    __syncthreads();
    s[t] += tmp;
    __syncthreads();
  }
  if (t < NBLK) boff[t] = s[t] - v;  // exclusive block offset
}

__global__ __launch_bounds__(256) void bfinal_k(const int* __restrict__ deg,
                                                const int* __restrict__ boff,
                                                int* __restrict__ rowstart,
                                                int* __restrict__ cursor,
                                                float* __restrict__ dinv) {
  __shared__ int s[256];
  const int t = threadIdx.x;
  const int i = blockIdx.x * 256 + t;
  const int d = (i < N_NODES) ? deg[i] : 0;
  s[t] = d;
  __syncthreads();
  for (int off = 1; off < 256; off <<= 1) {
    const int tmp = (t >= off) ? s[t - off] : 0;
    __syncthreads();
    s[t] += tmp;
    __syncthreads();
  }
  const int run = boff[blockIdx.x] + s[t] - d;  // exclusive prefix
  if (i < N_NODES) {
    rowstart[i] = run;
    cursor[i] = run;
    dinv[i] = rsqrtf((float)d + 1.0f);
    if (i == N_NODES - 1) rowstart[N_NODES] = run + d;
  }
}

__global__ __launch_bounds__(256) void fill_csr_k(const int* __restrict__ src,
                                                  const int* __restrict__ dst,
                                                  int* __restrict__ cursor,
                                                  int* __restrict__ csr_src) {
  const int e = blockIdx.x * 256 + threadIdx.x;
  if (e < N_EDGES) {
    const int pos = atomicAdd(&cursor[dst[e]], 1);
    csr_src[pos] = src[e];
  }
}

// ---------------------------------------------------------------------------
// Tiled SGEMM: H[n][m] = sum_k X[n][k]*W[m][k]  (+bias, relu optional)
// Tile: 128 nodes x 64 out-chans, BK=32. 256 threads, 8n x 4m per thread.
// LDS: As[32][132] + Bs[32][68] = 25.6 KB -> ~6 blocks/CU.
// ---------------------------------------------------------------------------
template <int K, int MTOT, bool BIASRELU>
__global__ __launch_bounds__(256) void gemm_tiled_k(const float* __restrict__ X,
                                                    const float* __restrict__ W,
                                                    const float* __restrict__ bias,
                                                    float* __restrict__ H) {
  constexpr int NT = 128, MT = 64, KT = 32;
  __shared__ float As[KT][NT + 4];
  __shared__ float Bs[KT][MT + 4];
  const int tid = threadIdx.x;
  const long n0 = (long)blockIdx.x * NT;
  const int m0 = blockIdx.y * MT;
  const int kq = tid & 7;       // k-quad within 32-k tile
  const int rowi = tid >> 3;    // 0..31
  const int tm = (tid & 15) * 4;  // m offset 0..60
  const int tn = (tid >> 4) * 4;  // n offset 0..60 (plus +64 half)

  float acc[8][4];
#pragma unroll
  for (int i = 0; i < 8; ++i)
#pragma unroll
    for (int j = 0; j < 4; ++j) acc[i][j] = 0.0f;

  for (int ks = 0; ks < K / KT; ++ks) {
    const int k0 = ks * KT;
    if (ks) __syncthreads();
    // Stage X-tile (128 rows x 32 k), transposed into As[k][n]
#pragma unroll
    for (int r = 0; r < 4; ++r) {
      const int nr = rowi + r * 32;
      long ng = n0 + nr;
      if (ng > N_NODES - 1) ng = N_NODES - 1;  // clamp; stores guarded
      const float4 v = *(const float4*)(X + ng * K + k0 + kq * 4);
      As[kq * 4 + 0][nr] = v.x;
      As[kq * 4 + 1][nr] = v.y;
      As[kq * 4 + 2][nr] = v.z;
      As[kq * 4 + 3][nr] = v.w;
    }
    // Stage W-tile (64 rows x 32 k), transposed into Bs[k][m]
#pragma unroll
    for (int r = 0; r < 2; ++r) {
      const int mr = rowi + r * 32;
      const float4 v = *(const float4*)(W + (long)(m0 + mr) * K + k0 + kq * 4);
      Bs[kq * 4 + 0][mr] = v.x;
      Bs[kq * 4 + 1][mr] = v.y;
      Bs[kq * 4 + 2][mr] = v.z;
      Bs[kq * 4 + 3][mr] = v.w;
    }
    __syncthreads();

#pragma unroll 4
    for (int k = 0; k < KT; ++k) {
      const float4 a0 = *(const float4*)&As[k][tn];
      const float4 a1 = *(const float4*)&As[k][tn + 64];
      const float4 b0 = *(const float4*)&Bs[k][tm];
      const float an[8] = {a0.x, a0.y, a0.z, a0.w, a1.x, a1.y, a1.z, a1.w};
      const float bm[4] = {b0.x, b0.y, b0.z, b0.w};
#pragma unroll
      for (int i = 0; i < 8; ++i)
#pragma unroll
        for (int j = 0; j < 4; ++j) acc[i][j] += an[i] * bm[j];
    }
  }

  float4 bv = {0.0f, 0.0f, 0.0f, 0.0f};
  if (BIASRELU) bv = *(const float4*)(bias + m0 + tm);
#pragma unroll
  for (int i = 0; i < 8; ++i) {
    const long ng = n0 + tn + (i & 3) + (i >> 2) * 64;
    if (ng < N_NODES) {
      float4 o = {acc[i][0], acc[i][1], acc[i][2], acc[i][3]};
      if (BIASRELU) {
        o.x = fmaxf(o.x + bv.x, 0.0f);
        o.y = fmaxf(o.y + bv.y, 0.0f);
        o.z = fmaxf(o.z + bv.z, 0.0f);
        o.w = fmaxf(o.w + bv.w, 0.0f);
      }
      *(float4*)(H + ng * MTOT + m0 + tm) = o;
    }
  }
}

// ---------------------------------------------------------------------------
// Gather-aggregate (one wave per destination node), C=128 -> 2 floats/lane.
// out[v] = (bias) + dinv[v]^2 * h[v] + sum_{e: dst=v} dinv[v]*dinv[src]*h[src]
// ---------------------------------------------------------------------------
template <int C, bool HAS_BIAS>
__global__ __launch_bounds__(256) void gather_k(const int* __restrict__ rowstart,
                                                const int* __restrict__ csr_src,
                                                const float* __restrict__ dinv,
                                                const float* __restrict__ h,
                                                const float* __restrict__ bias,
                                                float* __restrict__ out) {
  const int v = (blockIdx.x * 256 + threadIdx.x) >> 6;
  if (v >= N_NODES) return;
  const int lane = threadIdx.x & 63;
  constexpr int LPE = C / 64;
  const int rs = rowstart[v];
  const int re = rowstart[v + 1];
  const float dv = dinv[v];

  float acc[LPE];
#pragma unroll
  for (int i = 0; i < LPE; ++i) acc[i] = 0.0f;

  int e = rs;
  for (; e + 1 < re; e += 2) {
    const int s0 = csr_src[e];
    const int s1 = csr_src[e + 1];
    const float n0 = dv * dinv[s0];
    const float n1 = dv * dinv[s1];
    const float* p0 = h + (long)s0 * C + lane * LPE;
    const float* p1 = h + (long)s1 * C + lane * LPE;
    if constexpr (LPE == 4) {
      const float4 a = *(const float4*)p0;
      const float4 b = *(const float4*)p1;
      acc[0] += n0 * a.x + n1 * b.x;
      acc[1] += n0 * a.y + n1 * b.y;
      acc[2] += n0 * a.z + n1 * b.z;
      acc[3] += n0 * a.w + n1 * b.w;
    } else {
      const float2 a = *(const float2*)p0;
      const float2 b = *(const float2*)p1;
      acc[0] += n0 * a.x + n1 * b.x;
      acc[1] += n0 * a.y + n1 * b.y;
    }
  }
  if (e < re) {
    const int s0 = csr_src[e];
    const float n0 = dv * dinv[s0];
    const float* p0 = h + (long)s0 * C + lane * LPE;
    if constexpr (LPE == 4) {
      const float4 a = *(const float4*)p0;
      acc[0] += n0 * a.x;
      acc[1] += n0 * a.y;
      acc[2] += n0 * a.z;
      acc[3] += n0 * a.w;
    } else {
      const float2 a = *(const float2*)p0;
      acc[0] += n0 * a.x;
      acc[1] += n0 * a.y;
    }
  }

  const float s2 = dv * dv;
  const float* hp = h + (long)v * C + lane * LPE;
  float* op = out + (long)v * C + lane * LPE;
  if constexpr (LPE == 4) {
    const float4 hv = *(const float4*)hp;
    float4 o = {s2 * hv.x + acc[0], s2 * hv.y + acc[1], s2 * hv.z + acc[2],
                s2 * hv.w + acc[3]};
    if (HAS_BIAS) {
      const float4 bv = *(const float4*)(bias + lane * LPE);
      o.x += bv.x; o.y += bv.y; o.z += bv.z; o.w += bv.w;
    }
    *(float4*)op = o;
  } else {
    const float2 hv = *(const float2*)hp;
    float2 o = {s2 * hv.x + acc[0], s2 * hv.y + acc[1]};
    if (HAS_BIAS) {
      const float2 bv = *(const float2*)(bias + lane * LPE);
      o.x += bv.x; o.y += bv.y;
    }
    *(float2*)op = o;
  }
}

// ---------------------------------------------------------------------------
extern "C" void kernel_launch(void* const* d_in, const int* in_sizes, int n_in,
                              void* d_out, int out_size, void* d_ws, size_t ws_size,
                              hipStream_t stream) {
  (void)in_sizes; (void)n_in; (void)out_size; (void)ws_size;

  const float* x  = (const float*)d_in[0];
  const int*   ei = (const int*)d_in[1];
  const float* W1 = (const float*)d_in[2];
  const float* b1 = (const float*)d_in[3];
  const float* W2 = (const float*)d_in[4];
  const float* b2 = (const float*)d_in[5];
  float* out = (float*)d_out;

  // Workspace layout (bytes, 16B-aligned):
  char* ws = (char*)d_ws;
  int*   src      = (int*)(ws + 0);            //  3.2 MB
  int*   dst      = (int*)(ws + 3200000);      //  3.2 MB
  int*   csr_src  = (int*)(ws + 6400000);      //  3.2 MB
  int*   deg      = (int*)(ws + 9600000);      //  0.2 MB
  int*   rowstart = (int*)(ws + 9800000);      //  0.2 MB (N+1 ints)
  int*   cursor   = (int*)(ws + 10000016);     //  0.2 MB
  float* dinv     = (float*)(ws + 10200016);   //  0.2 MB
  int*   bsum     = (int*)(ws + 10400016);     //  ~1 KB (196 ints)
  int*   boff     = (int*)(ws + 10401040);     //  ~1 KB
  float* aggx     = (float*)(ws + 10500016);   // 25.6 MB (agg_x; reused as h2)
  float* h1       = (float*)(ws + 36100016);   // 51.2 MB
  float* h2       = aggx;                      // alias: aggx dead after gemm1

  const int EB  = (N_EDGES + 255) / 256;  // 3125
  const int GB  = (N_NODES + 3) / 4;      // gather: 4 waves/block, 1 node/wave
  const int NTB = (N_NODES + 127) / 128;  // 391 node-tiles for GEMM

  // ---- Graph preprocessing: CSR by destination + dinv ----
  deg_zero_k<<<NBLK, 256, 0, stream>>>(deg);
  convert_count_k<<<EB, 256, 0, stream>>>(ei, src, dst, deg);
  bsum_k<<<NBLK, 256, 0, stream>>>(deg, bsum);
  bscan_k<<<1, 256, 0, stream>>>(bsum, boff);
  bfinal_k<<<NBLK, 256, 0, stream>>>(deg, boff, rowstart, cursor, dinv);
  fill_csr_k<<<EB, 256, 0, stream>>>(src, dst, cursor, csr_src);

  // ---- Layer 1 (aggregate-first: agg(x)@W1^T == agg(x@W1^T)) ----
  gather_k<IN_C, false><<<GB, 256, 0, stream>>>(rowstart, csr_src, dinv, x,
                                                nullptr, aggx);
  gemm_tiled_k<IN_C, HID_C, true>
      <<<dim3(NTB, HID_C / 64), 256, 0, stream>>>(aggx, W1, b1, h1);

  // ---- Layer 2 (transform-first) ----
  gemm_tiled_k<HID_C, OUT_C, false>
      <<<dim3(NTB, OUT_C / 64), 256, 0, stream>>>(h1, W2, nullptr, h2);
  gather_k<OUT_C, true><<<GB, 256, 0, stream>>>(rowstart, csr_src, dinv, h2,
                                                b2, out);
}